// Round 11
// baseline (475.707 us; speedup 1.0000x reference)
//
#include <hip/hip_runtime.h>
#include <hip/hip_bf16.h>
#include <math.h>

#define KNN 16
#define CIN 128
#define COUT 128
#define D2 64
#define EPS 1e-5f

typedef __attribute__((ext_vector_type(8))) short short8;
typedef __attribute__((ext_vector_type(4))) float f32x4;
typedef unsigned int u32;
typedef unsigned short u16;

union S8U { short8 s; u32 u[4]; };

#define MFMA16(a, b, c) __builtin_amdgcn_mfma_f32_16x16x32_bf16((a), (b), (c), 0, 0, 0)

static __device__ __forceinline__ u16 f2bf(float f) {
  __hip_bfloat16 h = __float2bfloat16(f);
  u16 u; __builtin_memcpy(&u, &h, 2); return u;
}
#if __has_builtin(__builtin_amdgcn_cvt_pk_bf16_f32)
static __device__ __forceinline__ u32 pack2(float a, float b) {
  auto r = __builtin_amdgcn_cvt_pk_bf16_f32(a, b);  // v_cvt_pk_bf16_f32 (gfx950)
  u32 u; __builtin_memcpy(&u, &r, 4); return u;
}
#else
static __device__ __forceinline__ u32 pack2(float a, float b) {
  return (u32)f2bf(a) | ((u32)f2bf(b) << 16);
}
#endif
static __device__ __forceinline__ float bf_lo(u32 u) { return __uint_as_float(u << 16); }
static __device__ __forceinline__ float bf_hi(u32 u) { return __uint_as_float(u & 0xffff0000u); }

// gelu(x) ~= x * sigmoid(1.702 x); 1.702*log2(e) = 2.4555331
static __device__ __forceinline__ float gelu_fast(float x) {
  float e = __builtin_amdgcn_exp2f(x * -2.4555331f);
  return x * __builtin_amdgcn_rcpf(1.0f + e);
}

// max-reduce over the 16-lane DPP row (lanes l..l|15)
template <int CTRL>
static __device__ __forceinline__ float dppmax(float v) {
  int s = __builtin_bit_cast(int, v);
  int t = __builtin_amdgcn_update_dpp(s, s, CTRL, 0xf, 0xf, true);
  return fmaxf(v, __builtin_bit_cast(float, t));
}
static __device__ __forceinline__ float rowmax16(float v) {
  v = dppmax<0xB1>(v);   // quad_perm xor1
  v = dppmax<0x4E>(v);   // quad_perm xor2
  v = dppmax<0x141>(v);  // row_half_mirror
  v = dppmax<0x128>(v);  // row_ror:8
  return v;
}

// ---------- k_proj: xp = x @ W via MFMA (xp^T tiles), bf16-pair output ----------
// Also zeroes the BN partial-sum buffer (stream-ordered before k_lfa).
__global__ __launch_bounds__(256) void k_proj(const float* __restrict__ x,
                                              const float* __restrict__ W,
                                              u32* __restrict__ xp,
                                              float* __restrict__ part, int n) {
  const int t = threadIdx.x;
  if (blockIdx.x == 0 && t < 256) part[t] = 0.f;  // BN accumulator init

  __shared__ __align__(16) u32 Wf[8192];  // 32 frags (8 mt x 4 ks) x 256 u32
  for (int idx = t; idx < 8192; idx += 256) {
    int f = idx >> 8, rem = idx & 255;
    int l = rem >> 2, jp = rem & 3;
    int mt = f >> 2, ks = f & 3;
    int qq = l >> 4, mm = l & 15;
    int k = ks * 32 + qq * 8 + jp * 2;
    int c = mt * 16 + mm;
    Wf[idx] = pack2(W[(size_t)k * COUT + c], W[(size_t)(k + 1) * COUT + c]);
  }
  __syncthreads();

  const int wv = t >> 6, l = t & 63;
  const int q = l >> 4, m = l & 15;
  const short8* Wf8 = (const short8*)Wf;

  for (int tile = blockIdx.x * 4 + wv; tile * 16 < n; tile += gridDim.x * 4) {
    int r0 = tile * 16;
    int rr = min(r0 + m, n - 1);
    const float4* xr = (const float4*)(x + (size_t)rr * CIN);
    S8U xf[4];
#pragma unroll
    for (int ks = 0; ks < 4; ks++) {
      float4 a = xr[ks * 8 + q * 2];
      float4 b = xr[ks * 8 + q * 2 + 1];
      xf[ks].u[0] = pack2(a.x, a.y);
      xf[ks].u[1] = pack2(a.z, a.w);
      xf[ks].u[2] = pack2(b.x, b.y);
      xf[ks].u[3] = pack2(b.z, b.w);
    }
    bool ok = (r0 + m) < n;
    size_t rowb = (size_t)(r0 + m) * 64;
#pragma unroll
    for (int mt = 0; mt < 8; mt++) {
      f32x4 acc = {0.f, 0.f, 0.f, 0.f};
      __builtin_amdgcn_s_setprio(1);
#pragma unroll
      for (int ks = 0; ks < 4; ks++)
        acc = MFMA16(Wf8[(mt * 4 + ks) * 64 + l], xf[ks].s, acc);
      __builtin_amdgcn_s_setprio(0);
      if (ok) {
        uint2 v;
        v.x = pack2(acc[0], acc[1]);
        v.y = pack2(acc[2], acc[3]);
        *(uint2*)&xp[rowb + mt * 8 + q * 2] = v;
      }
    }
  }
}

// ---------- k_lfa: MFMA fused NCA + gather + max + BN-stats ----------
// v11: BN accumulation batched OUT of the mt loop.
//  - r9/r10 lesson: LDS atomics (RMW) in the mt loop serialize the in-order
//    LDS FIFO ahead of the next mt's fragment ds_reads: +30 us, regardless
//    of address contention (private slices changed nothing).
//  - fix: per mt, m==0 lanes stage the combined (sum, sumsq) float4s into
//    the idle sA scratch with two PLAIN ds_write_b128 (no RMW). Once per
//    iteration, all 64 lanes do ONE ds_read_b128 (lane (q,m): m<8 -> sum of
//    mt=m; m>=8 -> sumsq of mt=m-8) + 4 v_add into a 4-VGPR loop-carried
//    accumulator. Flush once per kernel: plain write to the wave's BN slice,
//    block reduction, 256 global atomics.
__global__ __launch_bounds__(1024, 4) void k_lfa(
    const float* __restrict__ xyz, const u32* __restrict__ xp,
    const int* __restrict__ knn,
    const float* __restrict__ m1w, const float* __restrict__ m1b,
    const float* __restrict__ m2w, const float* __restrict__ m2b,
    const float* __restrict__ m3aw, const float* __restrict__ m3ab,
    const float* __restrict__ m3bw, const float* __restrict__ m3bb,
    float* __restrict__ xsmax, float* __restrict__ part, int n) {
  // [0,73728) frags (m2 f0..7, m3a f8..39, m3b f40..71), [73728,74752) w14,
  // [74752,76032) biases, [76032,116992) per-wave scratch 16 x 2560 B,
  // [116992,133376) per-wave BN slices 16 x 256 floats (sum | sumsq)
  __shared__ __align__(16) char lds[133376];

  const int t = threadIdx.x, wv = t >> 6, l = t & 63;
  const int q = l >> 4, m = l & 15;

  {  // ---- per-block weight pack
    u32* lds32 = (u32*)lds;
    for (int idx = t; idx < 18432; idx += 1024) {
      int f = idx >> 8, rem = idx & 255;
      int ll = rem >> 2, jp = rem & 3;
      int qq = ll >> 4, mm = ll & 15;
      int j0 = jp * 2;
      float a, b;
      if (f < 8) {
        int mt = f >> 1, s = f & 1;
        const float* p = m2w + (size_t)(s * 32 + qq * 8 + j0) * D2 + mt * 16 + mm;
        a = p[0]; b = p[D2];
      } else if (f < 40) {
        int ff = f - 8; int mt = ff >> 2, s = ff & 3;
        const float* p = m3aw + (size_t)(s * 32 + qq * 8 + j0) * COUT + mt * 16 + mm;
        a = p[0]; b = p[COUT];
      } else {
        int ff = f - 40; int mt = ff >> 2, s = ff & 3;
        const float* p = m3bw + (size_t)(s * 32 + qq * 8 + j0) * COUT + mt * 16 + mm;
        a = p[0]; b = p[COUT];
      }
      lds32[idx] = pack2(a, b);
    }
    if (t < 64) {
      int p = (t & 32) + (t & 7) * 4 + ((t >> 3) & 3);
      ((float4*)(lds + 73728))[p] = make_float4(m1w[t], m1w[64 + t], m1w[128 + t], m1b[t]);
    }
    if (t < 320) {
      float* bias = (float*)(lds + 74752);
      bias[t] = (t < 64) ? m2b[t] : (t < 192) ? m3ab[t - 64] : m3bb[t - 192];
    }
  }
  __syncthreads();

  const char* fr = lds;
  const float4* w14 = (const float4*)(lds + 73728);
  const float* bias = (const float*)(lds + 74752);
  char* bnw = lds + 116992 + wv * 1024;  // wave-private BN slice (256 floats)
  char* sA = lds + 76032 + wv * 2560;
  char* sB = sA + 1280;

  // loop-carried BN accumulator: lane (q,m): m<8 -> sum[c=m*16+q*4+j],
  // m>=8 -> sumsq[c=(m-8)*16+q*4+j]
  f32x4 bna = {0.f, 0.f, 0.f, 0.f};
  const int bnoff = (m & 7) * 64 + (m >> 3) * 512 + q * 16;

  for (int pr = blockIdx.x * 16 + wv; pr * 2 < n; pr += gridDim.x * 16) {
    const int ptA = pr * 2;
    const int ptB = ptA + 1;
    const bool hasB = ptB < n;
    const int ptBc = hasB ? ptB : ptA;
    const int kidA = knn[(size_t)ptA * KNN + m];
    const int kidB = knn[(size_t)ptBc * KNN + m];

    // ---- prefetch epilogue gathers (compiler may sink; harmless)
    uint2 gA[8], gB[8];
#pragma unroll
    for (int mt = 0; mt < 8; mt++) {
      gA[mt] = *(const uint2*)(xp + (size_t)kidA * 64 + mt * 8 + q * 2);
      gB[mt] = *(const uint2*)(xp + (size_t)kidB * 64 + mt * 8 + q * 2);
    }

    float pxA = xyz[ptA * 3 + 0], pyA = xyz[ptA * 3 + 1], pzA = xyz[ptA * 3 + 2];
    float pxB = xyz[ptBc * 3 + 0], pyB = xyz[ptBc * 3 + 1], pzB = xyz[ptBc * 3 + 2];
    float axA = xyz[kidA * 3 + 0] - pxA, ayA = xyz[kidA * 3 + 1] - pyA, azA = xyz[kidA * 3 + 2] - pzA;
    float axB = xyz[kidB * 3 + 0] - pxB, ayB = xyz[kidB * 3 + 1] - pyB, azB = xyz[kidB * 3 + 2] - pzB;

    // ---- p0 rows in B-frag layout (registers)
    float p0A[16], p0B[16];
#pragma unroll
    for (int s = 0; s < 2; s++)
#pragma unroll
      for (int j = 0; j < 8; j++) {
        float4 w = w14[s * 32 + j * 4 + q];
        p0A[s * 8 + j] = fmaf(axA, w.x, fmaf(ayA, w.y, fmaf(azA, w.z, w.w)));
        p0B[s * 8 + j] = fmaf(axB, w.x, fmaf(ayB, w.y, fmaf(azB, w.z, w.w)));
      }
    S8U bp0A[2], bp0B[2], bplA[2], bplB[2];
#pragma unroll
    for (int s = 0; s < 2; s++)
#pragma unroll
      for (int jj = 0; jj < 4; jj++) {
        bp0A[s].u[jj] = pack2(p0A[s * 8 + 2 * jj], p0A[s * 8 + 2 * jj + 1]);
        bp0B[s].u[jj] = pack2(p0B[s * 8 + 2 * jj], p0B[s * 8 + 2 * jj + 1]);
      }
#pragma unroll
    for (int i = 0; i < 16; i++) { p0A[i] = rowmax16(p0A[i]); p0B[i] = rowmax16(p0B[i]); }
#pragma unroll
    for (int s = 0; s < 2; s++)
#pragma unroll
      for (int jj = 0; jj < 4; jj++) {
        bplA[s].u[jj] = pack2(p0A[s * 8 + 2 * jj], p0A[s * 8 + 2 * jj + 1]);
        bplB[s].u[jj] = pack2(p0B[s * 8 + 2 * jj], p0B[s * 8 + 2 * jj + 1]);
      }

    // ---- m2 -> p1 (sliced scratch) -> bpf frags
    short8 bpfA[2], bpfB[2];
#pragma unroll
    for (int s = 0; s < 2; s++) {
#pragma unroll
      for (int h = 0; h < 2; h++) {
        int mt = 2 * s + h;
        float4 bb = *(const float4*)&bias[mt * 16 + q * 4];
        f32x4 accA = {bb.x, bb.y, bb.z, bb.w};
        f32x4 accB = accA;
        __builtin_amdgcn_s_setprio(1);
#pragma unroll
        for (int ks = 0; ks < 2; ks++) {
          short8 af = *(const short8*)(fr + (mt * 2 + ks) * 1024 + l * 16);
          accA = MFMA16(af, bp0A[ks].s, accA);
          accB = MFMA16(af, bp0B[ks].s, accB);
        }
        __builtin_amdgcn_s_setprio(0);
        uint2 wA; wA.x = pack2(accA[0], accA[1]); wA.y = pack2(accA[2], accA[3]);
        uint2 wB; wB.x = pack2(accB[0], accB[1]); wB.y = pack2(accB[2], accB[3]);
        *(uint2*)(sA + m * 80 + h * 32 + q * 8) = wA;
        *(uint2*)(sB + m * 80 + h * 32 + q * 8) = wB;
      }
      bpfA[s] = *(const short8*)(sA + m * 80 + q * 16);
      bpfB[s] = *(const short8*)(sB + m * 80 + q * 16);
    }

    // ---- m3a -> gelu -> g (sliced scratch) -> bg frags
    short8 bgA[4], bgB[4];
#pragma unroll
    for (int s = 0; s < 4; s++) {
#pragma unroll
      for (int h = 0; h < 2; h++) {
        int mt = 2 * s + h;
        float4 bb = *(const float4*)&bias[64 + mt * 16 + q * 4];
        f32x4 accA = {bb.x, bb.y, bb.z, bb.w};
        f32x4 accB = accA;
        __builtin_amdgcn_s_setprio(1);
#pragma unroll
        for (int ks = 0; ks < 4; ks++) {
          short8 af = *(const short8*)(fr + (8 + mt * 4 + ks) * 1024 + l * 16);
          short8 bA = (ks == 0) ? bpfA[0] : (ks == 1) ? bpfA[1] : (ks == 2) ? bplA[0].s : bplA[1].s;
          short8 bB = (ks == 0) ? bpfB[0] : (ks == 1) ? bpfB[1] : (ks == 2) ? bplB[0].s : bplB[1].s;
          accA = MFMA16(af, bA, accA);
          accB = MFMA16(af, bB, accB);
        }
        __builtin_amdgcn_s_setprio(0);
        uint2 wA; wA.x = pack2(gelu_fast(accA[0]), gelu_fast(accA[1]));
        wA.y = pack2(gelu_fast(accA[2]), gelu_fast(accA[3]));
        uint2 wB; wB.x = pack2(gelu_fast(accB[0]), gelu_fast(accB[1]));
        wB.y = pack2(gelu_fast(accB[2]), gelu_fast(accB[3]));
        *(uint2*)(sA + m * 80 + h * 32 + q * 8) = wA;
        *(uint2*)(sB + m * 80 + h * 32 + q * 8) = wB;
      }
      bgA[s] = *(const short8*)(sA + m * 80 + q * 16);
      bgB[s] = *(const short8*)(sB + m * 80 + q * 16);
    }

    // ---- m3b + fused epilogue (pe in regs; gathers in gA/gB; BN staged)
#pragma unroll
    for (int mt = 0; mt < 8; mt++) {
      float4 bb = *(const float4*)&bias[192 + mt * 16 + q * 4];
      f32x4 accA = {bb.x, bb.y, bb.z, bb.w};
      f32x4 accB = accA;
      __builtin_amdgcn_s_setprio(1);
#pragma unroll
      for (int ks = 0; ks < 4; ks++) {
        short8 af = *(const short8*)(fr + (40 + mt * 4 + ks) * 1024 + l * 16);
        accA = MFMA16(af, bgA[ks], accA);
        accB = MFMA16(af, bgB[ks], accB);
      }
      __builtin_amdgcn_s_setprio(0);
      float4 oA, oB;
      {
        // self-row load: uniform in m -> broadcast; issued before the rowmax
        // chain so its latency hides under the DPP-max ops.
        uint2 sf = *(const uint2*)(xp + (size_t)ptA * 64 + mt * 8 + q * 2);
        float v0 = bf_lo(gA[mt].x) + accA[0];
        float v1 = bf_hi(gA[mt].x) + accA[1];
        float v2 = bf_lo(gA[mt].y) + accA[2];
        float v3 = bf_hi(gA[mt].y) + accA[3];
        v0 = rowmax16(v0); v1 = rowmax16(v1); v2 = rowmax16(v2); v3 = rowmax16(v3);
        if (m == 0) {
          oA = make_float4(v0 - bf_lo(sf.x), v1 - bf_hi(sf.x),
                           v2 - bf_lo(sf.y), v3 - bf_hi(sf.y));
          *(float4*)&xsmax[(size_t)ptA * COUT + mt * 16 + q * 4] = oA;
        }
      }
      {
        uint2 sf = *(const uint2*)(xp + (size_t)ptBc * 64 + mt * 8 + q * 2);
        float v0 = bf_lo(gB[mt].x) + accB[0];
        float v1 = bf_hi(gB[mt].x) + accB[1];
        float v2 = bf_lo(gB[mt].y) + accB[2];
        float v3 = bf_hi(gB[mt].y) + accB[3];
        v0 = rowmax16(v0); v1 = rowmax16(v1); v2 = rowmax16(v2); v3 = rowmax16(v3);
        if (m == 0) {
          oB = make_float4(v0 - bf_lo(sf.x), v1 - bf_hi(sf.x),
                           v2 - bf_lo(sf.y), v3 - bf_hi(sf.y));
          if (hasB)
            *(float4*)&xsmax[(size_t)ptB * COUT + mt * 16 + q * 4] = oB;
        }
      }
      if (m == 0) {
        // combined A+B contributions -> plain staged writes (no RMW)
        float bs = hasB ? 1.f : 0.f;
        float4 sv = make_float4(oA.x + bs * oB.x, oA.y + bs * oB.y,
                                oA.z + bs * oB.z, oA.w + bs * oB.w);
        float4 qv = make_float4(fmaf(bs * oB.x, oB.x, oA.x * oA.x),
                                fmaf(bs * oB.y, oB.y, oA.y * oA.y),
                                fmaf(bs * oB.z, oB.z, oA.z * oA.z),
                                fmaf(bs * oB.w, oB.w, oA.w * oA.w));
        *(float4*)(sA + mt * 64 + q * 16) = sv;
        *(float4*)(sA + 512 + mt * 64 + q * 16) = qv;
      }
    }

    // ---- per-iteration BN pickup: one b128 read + 4 adds (all 64 lanes)
    {
      float4 v = *(const float4*)(sA + bnoff);
      bna[0] += v.x; bna[1] += v.y; bna[2] += v.z; bna[3] += v.w;
    }
  }

  // ---- flush: plain write to wave slice, block-reduce, global atomic
  *(float4*)(bnw + bnoff) = make_float4(bna[0], bna[1], bna[2], bna[3]);
  __syncthreads();
  if (t < 256) {
    const float* bnall = (const float*)(lds + 116992);
    float s = 0.f;
#pragma unroll
    for (int w = 0; w < 16; w++) s += bnall[w * 256 + t];
    atomicAdd(&part[t], s);
  }
}

// ---------- BN stage 2: finalize mean/invstd from the fused sums ----------
__global__ void k_bnfinal(const float* __restrict__ part, float* __restrict__ ms,
                          int n) {
  int c = threadIdx.x;  // 128 threads
  float s = part[c];
  float s2 = part[128 + c];
  float inv_n = 1.0f / (float)n;
  float mean = s * inv_n;
  float var = s2 * inv_n - mean * mean;
  ms[c] = mean;
  ms[128 + c] = rsqrtf(var + EPS);
}

// ---------- BN normalize ----------
__global__ __launch_bounds__(256) void k_bnnorm(const float* __restrict__ xs,
                                                const float* __restrict__ ms,
                                                const float* __restrict__ gamma,
                                                const float* __restrict__ beta,
                                                float* __restrict__ out, int n) {
  size_t i = (size_t)blockIdx.x * 256 + threadIdx.x;
  size_t total4 = (size_t)n * (COUT / 4);
  if (i >= total4) return;
  int c = (int)((i * 4) & (COUT - 1));
  float4 v = ((const float4*)xs)[i];
  float4 mn = *(const float4*)&ms[c];
  float4 iv = *(const float4*)&ms[128 + c];
  float4 gm = *(const float4*)&gamma[c];
  float4 bt = *(const float4*)&beta[c];
  float4 o;
  o.x = (v.x - mn.x) * iv.x * gm.x + bt.x;
  o.y = (v.y - mn.y) * iv.y * gm.y + bt.y;
  o.z = (v.z - mn.z) * iv.z * gm.z + bt.z;
  o.w = (v.w - mn.w) * iv.w * gm.w + bt.w;
  ((float4*)out)[i] = o;
}

// ---------- launch ----------
extern "C" void kernel_launch(void* const* d_in, const int* in_sizes, int n_in,
                              void* d_out, int out_size, void* d_ws, size_t ws_size,
                              hipStream_t stream) {
  const float* xyz = (const float*)d_in[0];
  const float* x = (const float*)d_in[1];
  const int* knn = (const int*)d_in[2];
  const float* W = (const float*)d_in[3];
  const float* m1w = (const float*)d_in[4];
  const float* m1b = (const float*)d_in[5];
  const float* m2w = (const float*)d_in[6];
  const float* m2b = (const float*)d_in[7];
  const float* m3aw = (const float*)d_in[8];
  const float* m3ab = (const float*)d_in[9];
  const float* m3bw = (const float*)d_in[10];
  const float* m3bb = (const float*)d_in[11];
  const float* gamma = (const float*)d_in[12];
  const float* beta = (const float*)d_in[13];
  float* out = (float*)d_out;

  int n = in_sizes[0] / 3;

  char* ws = (char*)d_ws;
  u32* xp = (u32*)ws;                       // n * 256 B
  size_t o1 = (((size_t)n * 256 + 255) & ~(size_t)255);
  float* xsm = (float*)(ws + o1);           // n * 512 B
  size_t o2 = o1 + (((size_t)n * 512 + 255) & ~(size_t)255);
  float* part = (float*)(ws + o2);          // 256 floats (sum | sumsq)
  size_t o3 = o2 + 524288;
  float* ms = (float*)(ws + o3);            // 256 floats (mean | invstd)

  k_proj<<<1024, 256, 0, stream>>>(x, W, xp, part, n);
  k_lfa<<<256, 1024, 0, stream>>>(xyz, xp, knn, m1w, m1b, m2w, m2b,
                                  m3aw, m3ab, m3bw, m3bb, xsm, part, n);
  k_bnfinal<<<1, 128, 0, stream>>>(part, ms, n);
  k_bnnorm<<<(int)(((size_t)n * (COUT / 4) + 255) / 256), 256, 0, stream>>>(
      xsm, ms, gamma, beta, out, n);
}

// Round 12
// 473.218 us; speedup vs baseline: 1.0053x; 1.0053x over previous
//
#include <hip/hip_runtime.h>
#include <hip/hip_bf16.h>
#include <math.h>

#define KNN 16
#define CIN 128
#define COUT 128
#define D2 64
#define EPS 1e-5f

typedef __attribute__((ext_vector_type(8))) short short8;
typedef __attribute__((ext_vector_type(4))) float f32x4;
typedef unsigned int u32;
typedef unsigned short u16;

union S8U { short8 s; u32 u[4]; };

#define MFMA16(a, b, c) __builtin_amdgcn_mfma_f32_16x16x32_bf16((a), (b), (c), 0, 0, 0)

static __device__ __forceinline__ u16 f2bf(float f) {
  __hip_bfloat16 h = __float2bfloat16(f);
  u16 u; __builtin_memcpy(&u, &h, 2); return u;
}
#if __has_builtin(__builtin_amdgcn_cvt_pk_bf16_f32)
static __device__ __forceinline__ u32 pack2(float a, float b) {
  auto r = __builtin_amdgcn_cvt_pk_bf16_f32(a, b);  // v_cvt_pk_bf16_f32 (gfx950)
  u32 u; __builtin_memcpy(&u, &r, 4); return u;
}
#else
static __device__ __forceinline__ u32 pack2(float a, float b) {
  return (u32)f2bf(a) | ((u32)f2bf(b) << 16);
}
#endif
static __device__ __forceinline__ float bf_lo(u32 u) { return __uint_as_float(u << 16); }
static __device__ __forceinline__ float bf_hi(u32 u) { return __uint_as_float(u & 0xffff0000u); }

// gelu(x) ~= x * sigmoid(1.702 x); 1.702*log2(e) = 2.4555331
static __device__ __forceinline__ float gelu_fast(float x) {
  float e = __builtin_amdgcn_exp2f(x * -2.4555331f);
  return x * __builtin_amdgcn_rcpf(1.0f + e);
}

// max-reduce over the 16-lane DPP row (lanes l..l|15)
template <int CTRL>
static __device__ __forceinline__ float dppmax(float v) {
  int s = __builtin_bit_cast(int, v);
  int t = __builtin_amdgcn_update_dpp(s, s, CTRL, 0xf, 0xf, true);
  return fmaxf(v, __builtin_bit_cast(float, t));
}
static __device__ __forceinline__ float rowmax16(float v) {
  v = dppmax<0xB1>(v);   // quad_perm xor1
  v = dppmax<0x4E>(v);   // quad_perm xor2
  v = dppmax<0x141>(v);  // row_half_mirror
  v = dppmax<0x128>(v);  // row_ror:8
  return v;
}

// ---------- k_proj: xp = x @ W via MFMA (xp^T tiles), bf16-pair output ----------
// Also zeroes the BN partial-sum buffer (stream-ordered before k_lfa).
__global__ __launch_bounds__(256) void k_proj(const float* __restrict__ x,
                                              const float* __restrict__ W,
                                              u32* __restrict__ xp,
                                              float* __restrict__ part, int n) {
  const int t = threadIdx.x;
  if (blockIdx.x == 0 && t < 256) part[t] = 0.f;  // BN accumulator init

  __shared__ __align__(16) u32 Wf[8192];  // 32 frags (8 mt x 4 ks) x 256 u32
  for (int idx = t; idx < 8192; idx += 256) {
    int f = idx >> 8, rem = idx & 255;
    int l = rem >> 2, jp = rem & 3;
    int mt = f >> 2, ks = f & 3;
    int qq = l >> 4, mm = l & 15;
    int k = ks * 32 + qq * 8 + jp * 2;
    int c = mt * 16 + mm;
    Wf[idx] = pack2(W[(size_t)k * COUT + c], W[(size_t)(k + 1) * COUT + c]);
  }
  __syncthreads();

  const int wv = t >> 6, l = t & 63;
  const int q = l >> 4, m = l & 15;
  const short8* Wf8 = (const short8*)Wf;

  for (int tile = blockIdx.x * 4 + wv; tile * 16 < n; tile += gridDim.x * 4) {
    int r0 = tile * 16;
    int rr = min(r0 + m, n - 1);
    const float4* xr = (const float4*)(x + (size_t)rr * CIN);
    S8U xf[4];
#pragma unroll
    for (int ks = 0; ks < 4; ks++) {
      float4 a = xr[ks * 8 + q * 2];
      float4 b = xr[ks * 8 + q * 2 + 1];
      xf[ks].u[0] = pack2(a.x, a.y);
      xf[ks].u[1] = pack2(a.z, a.w);
      xf[ks].u[2] = pack2(b.x, b.y);
      xf[ks].u[3] = pack2(b.z, b.w);
    }
    bool ok = (r0 + m) < n;
    size_t rowb = (size_t)(r0 + m) * 64;
#pragma unroll
    for (int mt = 0; mt < 8; mt++) {
      f32x4 acc = {0.f, 0.f, 0.f, 0.f};
      __builtin_amdgcn_s_setprio(1);
#pragma unroll
      for (int ks = 0; ks < 4; ks++)
        acc = MFMA16(Wf8[(mt * 4 + ks) * 64 + l], xf[ks].s, acc);
      __builtin_amdgcn_s_setprio(0);
      if (ok) {
        uint2 v;
        v.x = pack2(acc[0], acc[1]);
        v.y = pack2(acc[2], acc[3]);
        *(uint2*)&xp[rowb + mt * 8 + q * 2] = v;
      }
    }
  }
}

// ---------- k_lfa: MFMA fused NCA + gather + max + BN-stats ----------
// v12: BN accumulation with ZERO loop-carried register state.
//  - r9-r11 lessons: the 64-VGPR allocation is razor-thin; LDS atomics in
//    the mt loop cost ~30 us (r9), and even a 4-VGPR loop-carried register
//    accumulator tips the allocator into progressive scratch spilling
//    (r10 FETCH+61/WRITE+56, r11 FETCH+87/WRITE+105).
//  - v12: per mt, m==0 lanes stage combined (sum,sumsq) float4s into idle
//    sA scratch with plain ds_write_b128 (as r11). Per iteration, each lane
//    does read-staging -> read-accumulator -> add -> write-accumulator on a
//    WAVE-PRIVATE LDS slice (lane-exclusive address: no atomic, no
//    loop-carried VGPR; temps die immediately). Flush: block-reduce the 16
//    slices + 256 global atomics.
__global__ __launch_bounds__(1024, 4) void k_lfa(
    const float* __restrict__ xyz, const u32* __restrict__ xp,
    const int* __restrict__ knn,
    const float* __restrict__ m1w, const float* __restrict__ m1b,
    const float* __restrict__ m2w, const float* __restrict__ m2b,
    const float* __restrict__ m3aw, const float* __restrict__ m3ab,
    const float* __restrict__ m3bw, const float* __restrict__ m3bb,
    float* __restrict__ xsmax, float* __restrict__ part, int n) {
  // [0,73728) frags (m2 f0..7, m3a f8..39, m3b f40..71), [73728,74752) w14,
  // [74752,76032) biases, [76032,116992) per-wave scratch 16 x 2560 B,
  // [116992,133376) per-wave BN slices 16 x 256 floats (sum | sumsq)
  __shared__ __align__(16) char lds[133376];

  const int t = threadIdx.x, wv = t >> 6, l = t & 63;
  const int q = l >> 4, m = l & 15;

  {  // ---- per-block weight pack
    u32* lds32 = (u32*)lds;
    for (int idx = t; idx < 18432; idx += 1024) {
      int f = idx >> 8, rem = idx & 255;
      int ll = rem >> 2, jp = rem & 3;
      int qq = ll >> 4, mm = ll & 15;
      int j0 = jp * 2;
      float a, b;
      if (f < 8) {
        int mt = f >> 1, s = f & 1;
        const float* p = m2w + (size_t)(s * 32 + qq * 8 + j0) * D2 + mt * 16 + mm;
        a = p[0]; b = p[D2];
      } else if (f < 40) {
        int ff = f - 8; int mt = ff >> 2, s = ff & 3;
        const float* p = m3aw + (size_t)(s * 32 + qq * 8 + j0) * COUT + mt * 16 + mm;
        a = p[0]; b = p[COUT];
      } else {
        int ff = f - 40; int mt = ff >> 2, s = ff & 3;
        const float* p = m3bw + (size_t)(s * 32 + qq * 8 + j0) * COUT + mt * 16 + mm;
        a = p[0]; b = p[COUT];
      }
      lds32[idx] = pack2(a, b);
    }
    if (t < 64) {
      int p = (t & 32) + (t & 7) * 4 + ((t >> 3) & 3);
      ((float4*)(lds + 73728))[p] = make_float4(m1w[t], m1w[64 + t], m1w[128 + t], m1b[t]);
    }
    if (t < 320) {
      float* bias = (float*)(lds + 74752);
      bias[t] = (t < 64) ? m2b[t] : (t < 192) ? m3ab[t - 64] : m3bb[t - 192];
    }
    float* bnall = (float*)(lds + 116992);
    for (int idx = t; idx < 4096; idx += 1024) bnall[idx] = 0.f;
  }
  __syncthreads();

  const char* fr = lds;
  const float4* w14 = (const float4*)(lds + 73728);
  const float* bias = (const float*)(lds + 74752);
  char* bnw = lds + 116992 + wv * 1024;  // wave-private BN slice (256 floats)
  char* sA = lds + 76032 + wv * 2560;
  char* sB = sA + 1280;

  // BN channel mapping: lane (q,m): m<8 -> sum[c=m*16+q*4+j],
  // m>=8 -> sumsq[c=(m-8)*16+q*4+j]
  const int bnoff = (m & 7) * 64 + (m >> 3) * 512 + q * 16;

  for (int pr = blockIdx.x * 16 + wv; pr * 2 < n; pr += gridDim.x * 16) {
    const int ptA = pr * 2;
    const int ptB = ptA + 1;
    const bool hasB = ptB < n;
    const int ptBc = hasB ? ptB : ptA;
    const int kidA = knn[(size_t)ptA * KNN + m];
    const int kidB = knn[(size_t)ptBc * KNN + m];

    // ---- prefetch epilogue gathers (compiler may sink; harmless)
    uint2 gA[8], gB[8];
#pragma unroll
    for (int mt = 0; mt < 8; mt++) {
      gA[mt] = *(const uint2*)(xp + (size_t)kidA * 64 + mt * 8 + q * 2);
      gB[mt] = *(const uint2*)(xp + (size_t)kidB * 64 + mt * 8 + q * 2);
    }

    float pxA = xyz[ptA * 3 + 0], pyA = xyz[ptA * 3 + 1], pzA = xyz[ptA * 3 + 2];
    float pxB = xyz[ptBc * 3 + 0], pyB = xyz[ptBc * 3 + 1], pzB = xyz[ptBc * 3 + 2];
    float axA = xyz[kidA * 3 + 0] - pxA, ayA = xyz[kidA * 3 + 1] - pyA, azA = xyz[kidA * 3 + 2] - pzA;
    float axB = xyz[kidB * 3 + 0] - pxB, ayB = xyz[kidB * 3 + 1] - pyB, azB = xyz[kidB * 3 + 2] - pzB;

    // ---- p0 rows in B-frag layout (registers)
    float p0A[16], p0B[16];
#pragma unroll
    for (int s = 0; s < 2; s++)
#pragma unroll
      for (int j = 0; j < 8; j++) {
        float4 w = w14[s * 32 + j * 4 + q];
        p0A[s * 8 + j] = fmaf(axA, w.x, fmaf(ayA, w.y, fmaf(azA, w.z, w.w)));
        p0B[s * 8 + j] = fmaf(axB, w.x, fmaf(ayB, w.y, fmaf(azB, w.z, w.w)));
      }
    S8U bp0A[2], bp0B[2], bplA[2], bplB[2];
#pragma unroll
    for (int s = 0; s < 2; s++)
#pragma unroll
      for (int jj = 0; jj < 4; jj++) {
        bp0A[s].u[jj] = pack2(p0A[s * 8 + 2 * jj], p0A[s * 8 + 2 * jj + 1]);
        bp0B[s].u[jj] = pack2(p0B[s * 8 + 2 * jj], p0B[s * 8 + 2 * jj + 1]);
      }
#pragma unroll
    for (int i = 0; i < 16; i++) { p0A[i] = rowmax16(p0A[i]); p0B[i] = rowmax16(p0B[i]); }
#pragma unroll
    for (int s = 0; s < 2; s++)
#pragma unroll
      for (int jj = 0; jj < 4; jj++) {
        bplA[s].u[jj] = pack2(p0A[s * 8 + 2 * jj], p0A[s * 8 + 2 * jj + 1]);
        bplB[s].u[jj] = pack2(p0B[s * 8 + 2 * jj], p0B[s * 8 + 2 * jj + 1]);
      }

    // ---- m2 -> p1 (sliced scratch) -> bpf frags
    short8 bpfA[2], bpfB[2];
#pragma unroll
    for (int s = 0; s < 2; s++) {
#pragma unroll
      for (int h = 0; h < 2; h++) {
        int mt = 2 * s + h;
        float4 bb = *(const float4*)&bias[mt * 16 + q * 4];
        f32x4 accA = {bb.x, bb.y, bb.z, bb.w};
        f32x4 accB = accA;
        __builtin_amdgcn_s_setprio(1);
#pragma unroll
        for (int ks = 0; ks < 2; ks++) {
          short8 af = *(const short8*)(fr + (mt * 2 + ks) * 1024 + l * 16);
          accA = MFMA16(af, bp0A[ks].s, accA);
          accB = MFMA16(af, bp0B[ks].s, accB);
        }
        __builtin_amdgcn_s_setprio(0);
        uint2 wA; wA.x = pack2(accA[0], accA[1]); wA.y = pack2(accA[2], accA[3]);
        uint2 wB; wB.x = pack2(accB[0], accB[1]); wB.y = pack2(accB[2], accB[3]);
        *(uint2*)(sA + m * 80 + h * 32 + q * 8) = wA;
        *(uint2*)(sB + m * 80 + h * 32 + q * 8) = wB;
      }
      bpfA[s] = *(const short8*)(sA + m * 80 + q * 16);
      bpfB[s] = *(const short8*)(sB + m * 80 + q * 16);
    }

    // ---- m3a -> gelu -> g (sliced scratch) -> bg frags
    short8 bgA[4], bgB[4];
#pragma unroll
    for (int s = 0; s < 4; s++) {
#pragma unroll
      for (int h = 0; h < 2; h++) {
        int mt = 2 * s + h;
        float4 bb = *(const float4*)&bias[64 + mt * 16 + q * 4];
        f32x4 accA = {bb.x, bb.y, bb.z, bb.w};
        f32x4 accB = accA;
        __builtin_amdgcn_s_setprio(1);
#pragma unroll
        for (int ks = 0; ks < 4; ks++) {
          short8 af = *(const short8*)(fr + (8 + mt * 4 + ks) * 1024 + l * 16);
          short8 bA = (ks == 0) ? bpfA[0] : (ks == 1) ? bpfA[1] : (ks == 2) ? bplA[0].s : bplA[1].s;
          short8 bB = (ks == 0) ? bpfB[0] : (ks == 1) ? bpfB[1] : (ks == 2) ? bplB[0].s : bplB[1].s;
          accA = MFMA16(af, bA, accA);
          accB = MFMA16(af, bB, accB);
        }
        __builtin_amdgcn_s_setprio(0);
        uint2 wA; wA.x = pack2(gelu_fast(accA[0]), gelu_fast(accA[1]));
        wA.y = pack2(gelu_fast(accA[2]), gelu_fast(accA[3]));
        uint2 wB; wB.x = pack2(gelu_fast(accB[0]), gelu_fast(accB[1]));
        wB.y = pack2(gelu_fast(accB[2]), gelu_fast(accB[3]));
        *(uint2*)(sA + m * 80 + h * 32 + q * 8) = wA;
        *(uint2*)(sB + m * 80 + h * 32 + q * 8) = wB;
      }
      bgA[s] = *(const short8*)(sA + m * 80 + q * 16);
      bgB[s] = *(const short8*)(sB + m * 80 + q * 16);
    }

    // ---- m3b + fused epilogue (pe in regs; gathers in gA/gB; BN staged)
#pragma unroll
    for (int mt = 0; mt < 8; mt++) {
      float4 bb = *(const float4*)&bias[192 + mt * 16 + q * 4];
      f32x4 accA = {bb.x, bb.y, bb.z, bb.w};
      f32x4 accB = accA;
      __builtin_amdgcn_s_setprio(1);
#pragma unroll
      for (int ks = 0; ks < 4; ks++) {
        short8 af = *(const short8*)(fr + (40 + mt * 4 + ks) * 1024 + l * 16);
        accA = MFMA16(af, bgA[ks], accA);
        accB = MFMA16(af, bgB[ks], accB);
      }
      __builtin_amdgcn_s_setprio(0);
      float4 oA, oB;
      {
        // self-row load: uniform in m -> broadcast; issued before the rowmax
        // chain so its latency hides under the DPP-max ops.
        uint2 sf = *(const uint2*)(xp + (size_t)ptA * 64 + mt * 8 + q * 2);
        float v0 = bf_lo(gA[mt].x) + accA[0];
        float v1 = bf_hi(gA[mt].x) + accA[1];
        float v2 = bf_lo(gA[mt].y) + accA[2];
        float v3 = bf_hi(gA[mt].y) + accA[3];
        v0 = rowmax16(v0); v1 = rowmax16(v1); v2 = rowmax16(v2); v3 = rowmax16(v3);
        if (m == 0) {
          oA = make_float4(v0 - bf_lo(sf.x), v1 - bf_hi(sf.x),
                           v2 - bf_lo(sf.y), v3 - bf_hi(sf.y));
          *(float4*)&xsmax[(size_t)ptA * COUT + mt * 16 + q * 4] = oA;
        }
      }
      {
        uint2 sf = *(const uint2*)(xp + (size_t)ptBc * 64 + mt * 8 + q * 2);
        float v0 = bf_lo(gB[mt].x) + accB[0];
        float v1 = bf_hi(gB[mt].x) + accB[1];
        float v2 = bf_lo(gB[mt].y) + accB[2];
        float v3 = bf_hi(gB[mt].y) + accB[3];
        v0 = rowmax16(v0); v1 = rowmax16(v1); v2 = rowmax16(v2); v3 = rowmax16(v3);
        if (m == 0) {
          oB = make_float4(v0 - bf_lo(sf.x), v1 - bf_hi(sf.x),
                           v2 - bf_lo(sf.y), v3 - bf_hi(sf.y));
          if (hasB)
            *(float4*)&xsmax[(size_t)ptB * COUT + mt * 16 + q * 4] = oB;
        }
      }
      if (m == 0) {
        // combined A+B contributions -> plain staged writes (no RMW)
        float bs = hasB ? 1.f : 0.f;
        float4 sv = make_float4(oA.x + bs * oB.x, oA.y + bs * oB.y,
                                oA.z + bs * oB.z, oA.w + bs * oB.w);
        float4 qv = make_float4(fmaf(bs * oB.x, oB.x, oA.x * oA.x),
                                fmaf(bs * oB.y, oB.y, oA.y * oA.y),
                                fmaf(bs * oB.z, oB.z, oA.z * oA.z),
                                fmaf(bs * oB.w, oB.w, oA.w * oA.w));
        *(float4*)(sA + mt * 64 + q * 16) = sv;
        *(float4*)(sA + 512 + mt * 64 + q * 16) = qv;
      }
    }

    // ---- per-iteration BN pickup: staged value -> wave-private LDS
    // accumulator (lane-exclusive address: plain read+add+write, no atomic,
    // no loop-carried VGPR)
    {
      float4 v = *(const float4*)(sA + bnoff);
      float4 a = *(const float4*)(bnw + bnoff);
      a.x += v.x; a.y += v.y; a.z += v.z; a.w += v.w;
      *(float4*)(bnw + bnoff) = a;
    }
  }

  // ---- flush: block-reduce the 16 wave slices, global atomic per slot
  __syncthreads();
  if (t < 256) {
    const float* bnall = (const float*)(lds + 116992);
    float s = 0.f;
#pragma unroll
    for (int w = 0; w < 16; w++) s += bnall[w * 256 + t];
    atomicAdd(&part[t], s);
  }
}

// ---------- BN normalize (bnfinal fused: per-block redundant stats) ----------
__global__ __launch_bounds__(256) void k_bnnorm(const float* __restrict__ xs,
                                                const float* __restrict__ part,
                                                const float* __restrict__ gamma,
                                                const float* __restrict__ beta,
                                                float* __restrict__ out, int n) {
  __shared__ float ms[256];
  int t = threadIdx.x;
  if (t < 128) {
    float inv_n = 1.0f / (float)n;
    float mean = part[t] * inv_n;
    float var = part[128 + t] * inv_n - mean * mean;
    ms[t] = mean;
    ms[128 + t] = rsqrtf(var + EPS);
  }
  __syncthreads();
  size_t i = (size_t)blockIdx.x * 256 + t;
  size_t total4 = (size_t)n * (COUT / 4);
  if (i >= total4) return;
  int c = (int)((i * 4) & (COUT - 1));
  float4 v = ((const float4*)xs)[i];
  float4 mn = *(const float4*)&ms[c];
  float4 iv = *(const float4*)&ms[128 + c];
  float4 gm = *(const float4*)&gamma[c];
  float4 bt = *(const float4*)&beta[c];
  float4 o;
  o.x = (v.x - mn.x) * iv.x * gm.x + bt.x;
  o.y = (v.y - mn.y) * iv.y * gm.y + bt.y;
  o.z = (v.z - mn.z) * iv.z * gm.z + bt.z;
  o.w = (v.w - mn.w) * iv.w * gm.w + bt.w;
  ((float4*)out)[i] = o;
}

// ---------- launch ----------
extern "C" void kernel_launch(void* const* d_in, const int* in_sizes, int n_in,
                              void* d_out, int out_size, void* d_ws, size_t ws_size,
                              hipStream_t stream) {
  const float* xyz = (const float*)d_in[0];
  const float* x = (const float*)d_in[1];
  const int* knn = (const int*)d_in[2];
  const float* W = (const float*)d_in[3];
  const float* m1w = (const float*)d_in[4];
  const float* m1b = (const float*)d_in[5];
  const float* m2w = (const float*)d_in[6];
  const float* m2b = (const float*)d_in[7];
  const float* m3aw = (const float*)d_in[8];
  const float* m3ab = (const float*)d_in[9];
  const float* m3bw = (const float*)d_in[10];
  const float* m3bb = (const float*)d_in[11];
  const float* gamma = (const float*)d_in[12];
  const float* beta = (const float*)d_in[13];
  float* out = (float*)d_out;

  int n = in_sizes[0] / 3;

  char* ws = (char*)d_ws;
  u32* xp = (u32*)ws;                       // n * 256 B
  size_t o1 = (((size_t)n * 256 + 255) & ~(size_t)255);
  float* xsm = (float*)(ws + o1);           // n * 512 B
  size_t o2 = o1 + (((size_t)n * 512 + 255) & ~(size_t)255);
  float* part = (float*)(ws + o2);          // 256 floats (sum | sumsq)

  k_proj<<<1024, 256, 0, stream>>>(x, W, xp, part, n);
  k_lfa<<<256, 1024, 0, stream>>>(xyz, xp, knn, m1w, m1b, m2w, m2b,
                                  m3aw, m3ab, m3bw, m3bb, xsm, part, n);
  k_bnnorm<<<(int)(((size_t)n * (COUT / 4) + 255) / 256), 256, 0, stream>>>(
      xsm, part, gamma, beta, out, n);
}

// Round 13
// 468.182 us; speedup vs baseline: 1.0161x; 1.0108x over previous
//
#include <hip/hip_runtime.h>
#include <hip/hip_bf16.h>
#include <math.h>

#define KNN 16
#define CIN 128
#define COUT 128
#define D2 64
#define EPS 1e-5f

typedef __attribute__((ext_vector_type(8))) short short8;
typedef __attribute__((ext_vector_type(4))) float f32x4;
typedef unsigned int u32;
typedef unsigned short u16;

union S8U { short8 s; u32 u[4]; };

#define MFMA16(a, b, c) __builtin_amdgcn_mfma_f32_16x16x32_bf16((a), (b), (c), 0, 0, 0)

static __device__ __forceinline__ u16 f2bf(float f) {
  __hip_bfloat16 h = __float2bfloat16(f);
  u16 u; __builtin_memcpy(&u, &h, 2); return u;
}
#if __has_builtin(__builtin_amdgcn_cvt_pk_bf16_f32)
static __device__ __forceinline__ u32 pack2(float a, float b) {
  auto r = __builtin_amdgcn_cvt_pk_bf16_f32(a, b);  // v_cvt_pk_bf16_f32 (gfx950)
  u32 u; __builtin_memcpy(&u, &r, 4); return u;
}
#else
static __device__ __forceinline__ u32 pack2(float a, float b) {
  return (u32)f2bf(a) | ((u32)f2bf(b) << 16);
}
#endif
static __device__ __forceinline__ float bf_lo(u32 u) { return __uint_as_float(u << 16); }
static __device__ __forceinline__ float bf_hi(u32 u) { return __uint_as_float(u & 0xffff0000u); }

// gelu(x) ~= x * sigmoid(1.702 x); 1.702*log2(e) = 2.4555331
static __device__ __forceinline__ float gelu_fast(float x) {
  float e = __builtin_amdgcn_exp2f(x * -2.4555331f);
  return x * __builtin_amdgcn_rcpf(1.0f + e);
}

// max-reduce over the 16-lane DPP row (lanes l..l|15)
template <int CTRL>
static __device__ __forceinline__ float dppmax(float v) {
  int s = __builtin_bit_cast(int, v);
  int t = __builtin_amdgcn_update_dpp(s, s, CTRL, 0xf, 0xf, true);
  return fmaxf(v, __builtin_bit_cast(float, t));
}
static __device__ __forceinline__ float rowmax16(float v) {
  v = dppmax<0xB1>(v);   // quad_perm xor1
  v = dppmax<0x4E>(v);   // quad_perm xor2
  v = dppmax<0x141>(v);  // row_half_mirror
  v = dppmax<0x128>(v);  // row_ror:8
  return v;
}

// ---------- k_proj: xp = x @ W via MFMA (xp^T tiles), bf16-pair output ----------
// Also zeroes the BN partial-sum buffer (stream-ordered before k_lfa).
__global__ __launch_bounds__(256) void k_proj(const float* __restrict__ x,
                                              const float* __restrict__ W,
                                              u32* __restrict__ xp,
                                              float* __restrict__ part, int n) {
  const int t = threadIdx.x;
  if (blockIdx.x == 0 && t < 256) part[t] = 0.f;  // BN accumulator init

  __shared__ __align__(16) u32 Wf[8192];  // 32 frags (8 mt x 4 ks) x 256 u32
  for (int idx = t; idx < 8192; idx += 256) {
    int f = idx >> 8, rem = idx & 255;
    int l = rem >> 2, jp = rem & 3;
    int mt = f >> 2, ks = f & 3;
    int qq = l >> 4, mm = l & 15;
    int k = ks * 32 + qq * 8 + jp * 2;
    int c = mt * 16 + mm;
    Wf[idx] = pack2(W[(size_t)k * COUT + c], W[(size_t)(k + 1) * COUT + c]);
  }
  __syncthreads();

  const int wv = t >> 6, l = t & 63;
  const int q = l >> 4, m = l & 15;
  const short8* Wf8 = (const short8*)Wf;

  for (int tile = blockIdx.x * 4 + wv; tile * 16 < n; tile += gridDim.x * 4) {
    int r0 = tile * 16;
    int rr = min(r0 + m, n - 1);
    const float4* xr = (const float4*)(x + (size_t)rr * CIN);
    S8U xf[4];
#pragma unroll
    for (int ks = 0; ks < 4; ks++) {
      float4 a = xr[ks * 8 + q * 2];
      float4 b = xr[ks * 8 + q * 2 + 1];
      xf[ks].u[0] = pack2(a.x, a.y);
      xf[ks].u[1] = pack2(a.z, a.w);
      xf[ks].u[2] = pack2(b.x, b.y);
      xf[ks].u[3] = pack2(b.z, b.w);
    }
    bool ok = (r0 + m) < n;
    size_t rowb = (size_t)(r0 + m) * 64;
#pragma unroll
    for (int mt = 0; mt < 8; mt++) {
      f32x4 acc = {0.f, 0.f, 0.f, 0.f};
      __builtin_amdgcn_s_setprio(1);
#pragma unroll
      for (int ks = 0; ks < 4; ks++)
        acc = MFMA16(Wf8[(mt * 4 + ks) * 64 + l], xf[ks].s, acc);
      __builtin_amdgcn_s_setprio(0);
      if (ok) {
        uint2 v;
        v.x = pack2(acc[0], acc[1]);
        v.y = pack2(acc[2], acc[3]);
        *(uint2*)&xp[rowb + mt * 8 + q * 2] = v;
      }
    }
  }
}

// ---------- k_lfa: MFMA fused NCA + gather + max, BN stats via epilogue re-read ----------
// v13: main loop is EXACTLY v8/r8 (327 us verified, zero spill). BN stats
// are computed in a POST-LOOP epilogue: after __syncthreads() (drains each
// wave's stores -> visible in L2), each wave re-reads the xsmax rows it
// itself wrote (lane l takes channels 2l,2l+1; float2, coalesced 512B/row,
// L2/L3-hot, ~200 KB/block) and accumulates sum/sumsq in registers whose
// live range BEGINS after the loop ends -> zero impact on the loop's
// razor-thin 64-VGPR allocation (the r9-r12 failure mode: ANY in-loop BN
// state costs ~33 us in spills/serialization).
__global__ __launch_bounds__(1024, 4) void k_lfa(
    const float* __restrict__ xyz, const u32* __restrict__ xp,
    const int* __restrict__ knn,
    const float* __restrict__ m1w, const float* __restrict__ m1b,
    const float* __restrict__ m2w, const float* __restrict__ m2b,
    const float* __restrict__ m3aw, const float* __restrict__ m3ab,
    const float* __restrict__ m3bw, const float* __restrict__ m3bb,
    float* __restrict__ xsmax, float* __restrict__ part, int n) {
  // [0,73728) frags (m2 f0..7, m3a f8..39, m3b f40..71), [73728,74752) w14,
  // [74752,76032) biases, [76032,116992) per-wave scratch 16 x 2560 B
  // (epilogue reuses [76032, 76032+16KB) as 16 x 256-float BN slices)
  __shared__ __align__(16) char lds[116992];

  const int t = threadIdx.x, wv = t >> 6, l = t & 63;
  const int q = l >> 4, m = l & 15;

  {  // ---- per-block weight pack
    u32* lds32 = (u32*)lds;
    for (int idx = t; idx < 18432; idx += 1024) {
      int f = idx >> 8, rem = idx & 255;
      int ll = rem >> 2, jp = rem & 3;
      int qq = ll >> 4, mm = ll & 15;
      int j0 = jp * 2;
      float a, b;
      if (f < 8) {
        int mt = f >> 1, s = f & 1;
        const float* p = m2w + (size_t)(s * 32 + qq * 8 + j0) * D2 + mt * 16 + mm;
        a = p[0]; b = p[D2];
      } else if (f < 40) {
        int ff = f - 8; int mt = ff >> 2, s = ff & 3;
        const float* p = m3aw + (size_t)(s * 32 + qq * 8 + j0) * COUT + mt * 16 + mm;
        a = p[0]; b = p[COUT];
      } else {
        int ff = f - 40; int mt = ff >> 2, s = ff & 3;
        const float* p = m3bw + (size_t)(s * 32 + qq * 8 + j0) * COUT + mt * 16 + mm;
        a = p[0]; b = p[COUT];
      }
      lds32[idx] = pack2(a, b);
    }
    if (t < 64) {
      int p = (t & 32) + (t & 7) * 4 + ((t >> 3) & 3);
      ((float4*)(lds + 73728))[p] = make_float4(m1w[t], m1w[64 + t], m1w[128 + t], m1b[t]);
    }
    if (t < 320) {
      float* bias = (float*)(lds + 74752);
      bias[t] = (t < 64) ? m2b[t] : (t < 192) ? m3ab[t - 64] : m3bb[t - 192];
    }
  }
  __syncthreads();

  const char* fr = lds;
  const float4* w14 = (const float4*)(lds + 73728);
  const float* bias = (const float*)(lds + 74752);
  char* sA = lds + 76032 + wv * 2560;
  char* sB = sA + 1280;

  for (int pr = blockIdx.x * 16 + wv; pr * 2 < n; pr += gridDim.x * 16) {
    const int ptA = pr * 2;
    const int ptB = ptA + 1;
    const bool hasB = ptB < n;
    const int ptBc = hasB ? ptB : ptA;
    const int kidA = knn[(size_t)ptA * KNN + m];
    const int kidB = knn[(size_t)ptBc * KNN + m];

    // ---- prefetch epilogue gathers (compiler may sink; harmless)
    uint2 gA[8], gB[8];
#pragma unroll
    for (int mt = 0; mt < 8; mt++) {
      gA[mt] = *(const uint2*)(xp + (size_t)kidA * 64 + mt * 8 + q * 2);
      gB[mt] = *(const uint2*)(xp + (size_t)kidB * 64 + mt * 8 + q * 2);
    }

    float pxA = xyz[ptA * 3 + 0], pyA = xyz[ptA * 3 + 1], pzA = xyz[ptA * 3 + 2];
    float pxB = xyz[ptBc * 3 + 0], pyB = xyz[ptBc * 3 + 1], pzB = xyz[ptBc * 3 + 2];
    float axA = xyz[kidA * 3 + 0] - pxA, ayA = xyz[kidA * 3 + 1] - pyA, azA = xyz[kidA * 3 + 2] - pzA;
    float axB = xyz[kidB * 3 + 0] - pxB, ayB = xyz[kidB * 3 + 1] - pyB, azB = xyz[kidB * 3 + 2] - pzB;

    // ---- p0 rows in B-frag layout (registers)
    float p0A[16], p0B[16];
#pragma unroll
    for (int s = 0; s < 2; s++)
#pragma unroll
      for (int j = 0; j < 8; j++) {
        float4 w = w14[s * 32 + j * 4 + q];
        p0A[s * 8 + j] = fmaf(axA, w.x, fmaf(ayA, w.y, fmaf(azA, w.z, w.w)));
        p0B[s * 8 + j] = fmaf(axB, w.x, fmaf(ayB, w.y, fmaf(azB, w.z, w.w)));
      }
    S8U bp0A[2], bp0B[2], bplA[2], bplB[2];
#pragma unroll
    for (int s = 0; s < 2; s++)
#pragma unroll
      for (int jj = 0; jj < 4; jj++) {
        bp0A[s].u[jj] = pack2(p0A[s * 8 + 2 * jj], p0A[s * 8 + 2 * jj + 1]);
        bp0B[s].u[jj] = pack2(p0B[s * 8 + 2 * jj], p0B[s * 8 + 2 * jj + 1]);
      }
#pragma unroll
    for (int i = 0; i < 16; i++) { p0A[i] = rowmax16(p0A[i]); p0B[i] = rowmax16(p0B[i]); }
#pragma unroll
    for (int s = 0; s < 2; s++)
#pragma unroll
      for (int jj = 0; jj < 4; jj++) {
        bplA[s].u[jj] = pack2(p0A[s * 8 + 2 * jj], p0A[s * 8 + 2 * jj + 1]);
        bplB[s].u[jj] = pack2(p0B[s * 8 + 2 * jj], p0B[s * 8 + 2 * jj + 1]);
      }

    // ---- m2 -> p1 (sliced scratch) -> bpf frags
    short8 bpfA[2], bpfB[2];
#pragma unroll
    for (int s = 0; s < 2; s++) {
#pragma unroll
      for (int h = 0; h < 2; h++) {
        int mt = 2 * s + h;
        float4 bb = *(const float4*)&bias[mt * 16 + q * 4];
        f32x4 accA = {bb.x, bb.y, bb.z, bb.w};
        f32x4 accB = accA;
        __builtin_amdgcn_s_setprio(1);
#pragma unroll
        for (int ks = 0; ks < 2; ks++) {
          short8 af = *(const short8*)(fr + (mt * 2 + ks) * 1024 + l * 16);
          accA = MFMA16(af, bp0A[ks].s, accA);
          accB = MFMA16(af, bp0B[ks].s, accB);
        }
        __builtin_amdgcn_s_setprio(0);
        uint2 wA; wA.x = pack2(accA[0], accA[1]); wA.y = pack2(accA[2], accA[3]);
        uint2 wB; wB.x = pack2(accB[0], accB[1]); wB.y = pack2(accB[2], accB[3]);
        *(uint2*)(sA + m * 80 + h * 32 + q * 8) = wA;
        *(uint2*)(sB + m * 80 + h * 32 + q * 8) = wB;
      }
      bpfA[s] = *(const short8*)(sA + m * 80 + q * 16);
      bpfB[s] = *(const short8*)(sB + m * 80 + q * 16);
    }

    // ---- m3a -> gelu -> g (sliced scratch) -> bg frags
    short8 bgA[4], bgB[4];
#pragma unroll
    for (int s = 0; s < 4; s++) {
#pragma unroll
      for (int h = 0; h < 2; h++) {
        int mt = 2 * s + h;
        float4 bb = *(const float4*)&bias[64 + mt * 16 + q * 4];
        f32x4 accA = {bb.x, bb.y, bb.z, bb.w};
        f32x4 accB = accA;
        __builtin_amdgcn_s_setprio(1);
#pragma unroll
        for (int ks = 0; ks < 4; ks++) {
          short8 af = *(const short8*)(fr + (8 + mt * 4 + ks) * 1024 + l * 16);
          short8 bA = (ks == 0) ? bpfA[0] : (ks == 1) ? bpfA[1] : (ks == 2) ? bplA[0].s : bplA[1].s;
          short8 bB = (ks == 0) ? bpfB[0] : (ks == 1) ? bpfB[1] : (ks == 2) ? bplB[0].s : bplB[1].s;
          accA = MFMA16(af, bA, accA);
          accB = MFMA16(af, bB, accB);
        }
        __builtin_amdgcn_s_setprio(0);
        uint2 wA; wA.x = pack2(gelu_fast(accA[0]), gelu_fast(accA[1]));
        wA.y = pack2(gelu_fast(accA[2]), gelu_fast(accA[3]));
        uint2 wB; wB.x = pack2(gelu_fast(accB[0]), gelu_fast(accB[1]));
        wB.y = pack2(gelu_fast(accB[2]), gelu_fast(accB[3]));
        *(uint2*)(sA + m * 80 + h * 32 + q * 8) = wA;
        *(uint2*)(sB + m * 80 + h * 32 + q * 8) = wB;
      }
      bgA[s] = *(const short8*)(sA + m * 80 + q * 16);
      bgB[s] = *(const short8*)(sB + m * 80 + q * 16);
    }

    // ---- m3b + fused epilogue (pe in regs; gathers in gA/gB)
#pragma unroll
    for (int mt = 0; mt < 8; mt++) {
      float4 bb = *(const float4*)&bias[192 + mt * 16 + q * 4];
      f32x4 accA = {bb.x, bb.y, bb.z, bb.w};
      f32x4 accB = accA;
      __builtin_amdgcn_s_setprio(1);
#pragma unroll
      for (int ks = 0; ks < 4; ks++) {
        short8 af = *(const short8*)(fr + (40 + mt * 4 + ks) * 1024 + l * 16);
        accA = MFMA16(af, bgA[ks], accA);
        accB = MFMA16(af, bgB[ks], accB);
      }
      __builtin_amdgcn_s_setprio(0);
      {
        // self-row load: uniform in m -> broadcast; issued before the rowmax
        // chain so its latency hides under the DPP-max ops.
        uint2 sf = *(const uint2*)(xp + (size_t)ptA * 64 + mt * 8 + q * 2);
        float v0 = bf_lo(gA[mt].x) + accA[0];
        float v1 = bf_hi(gA[mt].x) + accA[1];
        float v2 = bf_lo(gA[mt].y) + accA[2];
        float v3 = bf_hi(gA[mt].y) + accA[3];
        v0 = rowmax16(v0); v1 = rowmax16(v1); v2 = rowmax16(v2); v3 = rowmax16(v3);
        if (m == 0) {
          float4 o = make_float4(v0 - bf_lo(sf.x), v1 - bf_hi(sf.x),
                                 v2 - bf_lo(sf.y), v3 - bf_hi(sf.y));
          *(float4*)&xsmax[(size_t)ptA * COUT + mt * 16 + q * 4] = o;
        }
      }
      {
        uint2 sf = *(const uint2*)(xp + (size_t)ptBc * 64 + mt * 8 + q * 2);
        float v0 = bf_lo(gB[mt].x) + accB[0];
        float v1 = bf_hi(gB[mt].x) + accB[1];
        float v2 = bf_lo(gB[mt].y) + accB[2];
        float v3 = bf_hi(gB[mt].y) + accB[3];
        v0 = rowmax16(v0); v1 = rowmax16(v1); v2 = rowmax16(v2); v3 = rowmax16(v3);
        if (hasB && m == 0) {
          float4 o = make_float4(v0 - bf_lo(sf.x), v1 - bf_hi(sf.x),
                                 v2 - bf_lo(sf.y), v3 - bf_hi(sf.y));
          *(float4*)&xsmax[(size_t)ptB * COUT + mt * 16 + q * 4] = o;
        }
      }
    }
  }

  // ---- BN stats epilogue: re-read own rows (L2-hot), reduce, one atomic ----
  // Barrier drains all waves' stores (s_waitcnt vmcnt(0) before s_barrier)
  // and retires the sA scratch so it can be reused for the BN slices.
  __syncthreads();
  {
    float s0 = 0.f, s1 = 0.f, q0 = 0.f, q1 = 0.f;
    for (int pr = blockIdx.x * 16 + wv; pr * 2 < n; pr += gridDim.x * 16) {
      int ptA = pr * 2, ptB = ptA + 1;
      float2 a = *(const float2*)&xsmax[(size_t)ptA * COUT + l * 2];
      s0 += a.x; s1 += a.y; q0 = fmaf(a.x, a.x, q0); q1 = fmaf(a.y, a.y, q1);
      if (ptB < n) {
        float2 b = *(const float2*)&xsmax[(size_t)ptB * COUT + l * 2];
        s0 += b.x; s1 += b.y; q0 = fmaf(b.x, b.x, q0); q1 = fmaf(b.y, b.y, q1);
      }
    }
    float* slice = (float*)(lds + 76032) + wv * 256;
    slice[l * 2 + 0] = s0;
    slice[l * 2 + 1] = s1;
    slice[128 + l * 2 + 0] = q0;
    slice[128 + l * 2 + 1] = q1;
  }
  __syncthreads();
  if (t < 256) {
    const float* slices = (const float*)(lds + 76032);
    float s = 0.f;
#pragma unroll
    for (int w = 0; w < 16; w++) s += slices[w * 256 + t];
    atomicAdd(&part[t], s);
  }
}

// ---------- BN normalize (bnfinal fused: per-block redundant stats) ----------
__global__ __launch_bounds__(256) void k_bnnorm(const float* __restrict__ xs,
                                                const float* __restrict__ part,
                                                const float* __restrict__ gamma,
                                                const float* __restrict__ beta,
                                                float* __restrict__ out, int n) {
  __shared__ float ms[256];
  int t = threadIdx.x;
  if (t < 128) {
    float inv_n = 1.0f / (float)n;
    float mean = part[t] * inv_n;
    float var = part[128 + t] * inv_n - mean * mean;
    ms[t] = mean;
    ms[128 + t] = rsqrtf(var + EPS);
  }
  __syncthreads();
  size_t i = (size_t)blockIdx.x * 256 + t;
  size_t total4 = (size_t)n * (COUT / 4);
  if (i >= total4) return;
  int c = (int)((i * 4) & (COUT - 1));
  float4 v = ((const float4*)xs)[i];
  float4 mn = *(const float4*)&ms[c];
  float4 iv = *(const float4*)&ms[128 + c];
  float4 gm = *(const float4*)&gamma[c];
  float4 bt = *(const float4*)&beta[c];
  float4 o;
  o.x = (v.x - mn.x) * iv.x * gm.x + bt.x;
  o.y = (v.y - mn.y) * iv.y * gm.y + bt.y;
  o.z = (v.z - mn.z) * iv.z * gm.z + bt.z;
  o.w = (v.w - mn.w) * iv.w * gm.w + bt.w;
  ((float4*)out)[i] = o;
}

// ---------- launch ----------
extern "C" void kernel_launch(void* const* d_in, const int* in_sizes, int n_in,
                              void* d_out, int out_size, void* d_ws, size_t ws_size,
                              hipStream_t stream) {
  const float* xyz = (const float*)d_in[0];
  const float* x = (const float*)d_in[1];
  const int* knn = (const int*)d_in[2];
  const float* W = (const float*)d_in[3];
  const float* m1w = (const float*)d_in[4];
  const float* m1b = (const float*)d_in[5];
  const float* m2w = (const float*)d_in[6];
  const float* m2b = (const float*)d_in[7];
  const float* m3aw = (const float*)d_in[8];
  const float* m3ab = (const float*)d_in[9];
  const float* m3bw = (const float*)d_in[10];
  const float* m3bb = (const float*)d_in[11];
  const float* gamma = (const float*)d_in[12];
  const float* beta = (const float*)d_in[13];
  float* out = (float*)d_out;

  int n = in_sizes[0] / 3;

  char* ws = (char*)d_ws;
  u32* xp = (u32*)ws;                       // n * 256 B
  size_t o1 = (((size_t)n * 256 + 255) & ~(size_t)255);
  float* xsm = (float*)(ws + o1);           // n * 512 B
  size_t o2 = o1 + (((size_t)n * 512 + 255) & ~(size_t)255);
  float* part = (float*)(ws + o2);          // 256 floats (sum | sumsq)

  k_proj<<<1024, 256, 0, stream>>>(x, W, xp, part, n);
  k_lfa<<<256, 1024, 0, stream>>>(xyz, xp, knn, m1w, m1b, m2w, m2b,
                                  m3aw, m3ab, m3bw, m3bb, xsm, part, n);
  k_bnnorm<<<(int)(((size_t)n * (COUT / 4) + 255) / 256), 256, 0, stream>>>(
      xsm, part, gamma, beta, out, n);
}